// Round 1
// baseline (239.804 us; speedup 1.0000x reference)
//
#include <hip/hip_runtime.h>
#include <hip/hip_bf16.h>

// SRU layer: LN -> bf16 MFMA GEMM (u,f,r) -> chunked linear scan -> output.
// L=2048, B=8, D=1024, M=L*B=16384, K=D=1024, N=3*D=3072.

typedef unsigned short u16;
typedef __bf16 bf16x8 __attribute__((ext_vector_type(8)));
typedef float f32x4 __attribute__((ext_vector_type(4)));

#define L_DIM 2048
#define B_DIM 8
#define D_DIM 1024
#define M_DIM (L_DIM * B_DIM)   // 16384
#define K_DIM D_DIM             // 1024
#define N_DIM (3 * D_DIM)       // 3072
#define NCH 32                  // scan chunks
#define CLEN (L_DIM / NCH)      // 64

__device__ __forceinline__ float bf2f(u16 h) {
    unsigned int u = ((unsigned int)h) << 16;
    float f;
    __builtin_memcpy(&f, &u, 4);
    return f;
}

__device__ __forceinline__ u16 f2bf(float f) {
    unsigned int u;
    __builtin_memcpy(&u, &f, 4);
    u = u + 0x7fff + ((u >> 16) & 1);   // RNE
    return (u16)(u >> 16);
}

__device__ __forceinline__ void async16(void* lds, const void* g) {
    __builtin_amdgcn_global_load_lds(
        (const __attribute__((address_space(1))) void*)g,
        (__attribute__((address_space(3))) void*)lds, 16, 0, 0);
}

// ---------------- LayerNorm: one block (256 thr) per row of 1024 ----------------
__global__ __launch_bounds__(256) void ln_kernel(const float* __restrict__ x,
                                                 const float* __restrict__ gamma,
                                                 const float* __restrict__ beta,
                                                 u16* __restrict__ xn) {
    int row = blockIdx.x;
    int tid = threadIdx.x;
    const float4* xr = (const float4*)(x + (size_t)row * D_DIM);
    float4 v = xr[tid];
    float s = v.x + v.y + v.z + v.w;
    float q = v.x * v.x + v.y * v.y + v.z * v.z + v.w * v.w;
    #pragma unroll
    for (int off = 32; off; off >>= 1) {
        s += __shfl_down(s, off);
        q += __shfl_down(q, off);
    }
    __shared__ float ss[4], qq[4];
    int lane = tid & 63, wv = tid >> 6;
    if (lane == 0) { ss[wv] = s; qq[wv] = q; }
    __syncthreads();
    s = ss[0] + ss[1] + ss[2] + ss[3];
    q = qq[0] + qq[1] + qq[2] + qq[3];
    float mu = s * (1.0f / D_DIM);
    float var = q * (1.0f / D_DIM) - mu * mu;
    float rs = rsqrtf(var + 1e-5f);
    float4 g = ((const float4*)gamma)[tid];
    float4 bt = ((const float4*)beta)[tid];
    ushort4 o;
    o.x = f2bf((v.x - mu) * rs * g.x + bt.x);
    o.y = f2bf((v.y - mu) * rs * g.y + bt.y);
    o.z = f2bf((v.z - mu) * rs * g.z + bt.z);
    o.w = f2bf((v.w - mu) * rs * g.w + bt.w);
    ((ushort4*)(xn + (size_t)row * D_DIM))[tid] = o;
}

// ---------------- W transpose+convert: W[K][N] f32 -> Wt[N][K] bf16 ----------------
__global__ __launch_bounds__(256) void wt_kernel(const float* __restrict__ W,
                                                 u16* __restrict__ Wt) {
    __shared__ float t[64][65];
    int k0 = blockIdx.x * 64;
    int n0 = blockIdx.y * 64;
    int col = threadIdx.x & 63;
    int rg4 = threadIdx.x >> 6;
    #pragma unroll
    for (int j = 0; j < 16; ++j) {
        int r = rg4 * 16 + j;
        t[r][col] = W[(size_t)(k0 + r) * N_DIM + n0 + col];
    }
    __syncthreads();
    #pragma unroll
    for (int j = 0; j < 16; ++j) {
        int nr = rg4 * 16 + j;
        Wt[(size_t)(n0 + nr) * K_DIM + k0 + col] = f2bf(t[col][nr]);
    }
}

// ---------------- GEMM: C = A[M,K] x Bt[N,K]^T, epilogue bias+sigmoid ----------------
// 128x128 tile, BK=64, 4 waves (2x2), 16x16x32 bf16 MFMA, XOR-swizzled LDS.
__global__ __launch_bounds__(256) void gemm_kernel(const u16* __restrict__ A,
                                                   const u16* __restrict__ Bt,
                                                   const float* __restrict__ bias,
                                                   u16* __restrict__ uo,
                                                   u16* __restrict__ fo,
                                                   u16* __restrict__ ro) {
    __shared__ char lds[32768];
    char* ldsA = lds;
    char* ldsB = lds + 16384;
    int tid = threadIdx.x;
    int wave = tid >> 6, lane = tid & 63;
    int lm = lane & 15, lg = lane >> 4;
    int m0 = blockIdx.x * 128;
    int n0 = blockIdx.y * 128;
    int wm = wave >> 1, wn = wave & 1;

    f32x4 acc[4][4] = {};

    for (int kt = 0; kt < K_DIM / 64; ++kt) {
        int k0 = kt * 64;
        // stage A and Bt tiles: each [128 rows][64 cols] bf16 = 16KB each.
        // Linear LDS dest; XOR-swizzle applied on the GLOBAL source (chunk ^= row&7).
        #pragma unroll
        for (int i = 0; i < 4; ++i) {
            int c = i * 256 + tid;          // 16B-chunk index 0..1023
            int row = c >> 3;               // 0..127
            int colL = (c & 7) ^ (row & 7); // logical 16B column
            const u16* ga = A + (size_t)(m0 + row) * K_DIM + k0 + colL * 8;
            async16(ldsA + i * 4096 + wave * 1024, ga);
            const u16* gb = Bt + (size_t)(n0 + row) * K_DIM + k0 + colL * 8;
            async16(ldsB + i * 4096 + wave * 1024, gb);
        }
        __syncthreads();
        #pragma unroll
        for (int kk = 0; kk < 2; ++kk) {
            bf16x8 av[4], bv[4];
            #pragma unroll
            for (int f = 0; f < 4; ++f) {
                int rowA = wm * 64 + f * 16 + lm;
                av[f] = *(const bf16x8*)(ldsA + rowA * 128 + (((kk * 4 + lg) ^ (rowA & 7)) << 4));
                int rowB = wn * 64 + f * 16 + lm;
                bv[f] = *(const bf16x8*)(ldsB + rowB * 128 + (((kk * 4 + lg) ^ (rowB & 7)) << 4));
            }
            #pragma unroll
            for (int fm = 0; fm < 4; ++fm)
                #pragma unroll
                for (int fn = 0; fn < 4; ++fn)
                    acc[fm][fn] = __builtin_amdgcn_mfma_f32_16x16x32_bf16(
                        av[fm], bv[fn], acc[fm][fn], 0, 0, 0);
        }
        __syncthreads();
    }

    // epilogue: bias add; sigmoid for f/r segments; store bf16.
    int seg = n0 >> 10;  // uniform per block since 1024 % 128 == 0
    u16* outp = (seg == 0) ? uo : ((seg == 1) ? fo : ro);
    #pragma unroll
    for (int fn = 0; fn < 4; ++fn) {
        #pragma unroll
        for (int fm = 0; fm < 4; ++fm) {
            int col = n0 + wn * 64 + fn * 16 + lm;     // D-layout: col = lane&15
            int cm = col & 1023;
            float bb = bias[col];
            #pragma unroll
            for (int j = 0; j < 4; ++j) {
                int row = m0 + wm * 64 + fm * 16 + lg * 4 + j;  // row = (lane>>4)*4 + j
                float val = acc[fm][fn][j] + bb;
                if (seg != 0) val = 1.0f / (1.0f + __expf(-val));  // sigmoid
                outp[(size_t)row * D_DIM + cm] = f2bf(val);
            }
        }
    }
}

// ---------------- Scan phase 1: per-chunk (prod f, partial sum), 2 chains/thread ----------------
__global__ __launch_bounds__(256) void scan1_kernel(const u16* __restrict__ fg,
                                                    const u16* __restrict__ u,
                                                    float* __restrict__ Aa,
                                                    float* __restrict__ Ss) {
    int ch = blockIdx.x;
    int bd = (blockIdx.y * 256 + threadIdx.x) * 2;
    int b = bd >> 10, d = bd & 1023;
    float a0 = 1.0f, a1 = 1.0f, s0 = 0.0f, s1 = 0.0f;
    for (int t = ch * CLEN; t < ch * CLEN + CLEN; ++t) {
        size_t idx = ((size_t)(t * B_DIM + b) << 10) + d;
        ushort2 f2 = *(const ushort2*)(fg + idx);
        ushort2 u2 = *(const ushort2*)(u + idx);
        float f0 = bf2f(f2.x), f1 = bf2f(f2.y);
        float v0 = bf2f(u2.x), v1 = bf2f(u2.y);
        s0 = f0 * s0 + (1.0f - f0) * v0;
        s1 = f1 * s1 + (1.0f - f1) * v1;
        a0 *= f0;
        a1 *= f1;
    }
    int o = ch * 8192 + bd;
    *(float2*)(Aa + o) = make_float2(a0, a1);
    *(float2*)(Ss + o) = make_float2(s0, s1);
}

// ---------------- Scan phase 2: sequential over chunks (tiny) ----------------
__global__ __launch_bounds__(256) void scan2_kernel(const float* __restrict__ Aa,
                                                    const float* __restrict__ Ss,
                                                    const float* __restrict__ c0,
                                                    float* __restrict__ cs,
                                                    float* __restrict__ lastc) {
    int bd = blockIdx.x * 256 + threadIdx.x;  // 0..8191
    float c = c0[bd];
    #pragma unroll 4
    for (int ch = 0; ch < NCH; ++ch) {
        cs[ch * 8192 + bd] = c;
        c = Aa[ch * 8192 + bd] * c + Ss[ch * 8192 + bd];
    }
    lastc[bd] = c;
}

// ---------------- Scan phase 3: replay chunk + epilogue, write output ----------------
__global__ __launch_bounds__(256) void scan3_kernel(const float* __restrict__ cs,
                                                    const u16* __restrict__ fg,
                                                    const u16* __restrict__ u,
                                                    const u16* __restrict__ rg,
                                                    const u16* __restrict__ xn,
                                                    const float* __restrict__ x,
                                                    float* __restrict__ out) {
    int ch = blockIdx.x;
    int bd = (blockIdx.y * 256 + threadIdx.x) * 2;
    int b = bd >> 10, d = bd & 1023;
    float c0v = cs[ch * 8192 + bd];
    float c1v = cs[ch * 8192 + bd + 1];
    for (int t = ch * CLEN; t < ch * CLEN + CLEN; ++t) {
        size_t idx = ((size_t)(t * B_DIM + b) << 10) + d;
        ushort2 f2 = *(const ushort2*)(fg + idx);
        ushort2 u2 = *(const ushort2*)(u + idx);
        ushort2 r2 = *(const ushort2*)(rg + idx);
        ushort2 n2 = *(const ushort2*)(xn + idx);
        float2 x2 = *(const float2*)(x + idx);
        float f0 = bf2f(f2.x), f1 = bf2f(f2.y);
        float v0 = bf2f(u2.x), v1 = bf2f(u2.y);
        float r0 = bf2f(r2.x), r1 = bf2f(r2.y);
        float n0 = bf2f(n2.x), n1 = bf2f(n2.y);
        c0v = f0 * c0v + (1.0f - f0) * v0;
        c1v = f1 * c1v + (1.0f - f1) * v1;
        float h0 = r0 * tanhf(c0v) + (1.0f - r0) * n0;
        float h1 = r1 * tanhf(c1v) + (1.0f - r1) * n1;
        *(float2*)(out + idx) = make_float2(x2.x + h0, x2.y + h1);
    }
}

extern "C" void kernel_launch(void* const* d_in, const int* in_sizes, int n_in,
                              void* d_out, int out_size, void* d_ws, size_t ws_size,
                              hipStream_t stream) {
    const float* x     = (const float*)d_in[0];
    const float* c0    = (const float*)d_in[1];
    const float* W     = (const float*)d_in[2];
    const float* b     = (const float*)d_in[3];
    const float* gamma = (const float*)d_in[4];
    const float* beta  = (const float*)d_in[5];
    float* out = (float*)d_out;
    float* lastc = out + (size_t)M_DIM * D_DIM;

    // ws layout (needs ~137 MB)
    char* w = (char*)d_ws;
    u16* xn = (u16*)w;  w += (size_t)M_DIM * D_DIM * 2;   // 32 MB
    u16* Wt = (u16*)w;  w += (size_t)N_DIM * K_DIM * 2;   // 6 MB
    u16* ug = (u16*)w;  w += (size_t)M_DIM * D_DIM * 2;   // 32 MB
    u16* fg = (u16*)w;  w += (size_t)M_DIM * D_DIM * 2;   // 32 MB
    u16* rg = (u16*)w;  w += (size_t)M_DIM * D_DIM * 2;   // 32 MB
    float* Aa = (float*)w; w += (size_t)NCH * 8192 * 4;   // 1 MB
    float* Ss = (float*)w; w += (size_t)NCH * 8192 * 4;   // 1 MB
    float* cs = (float*)w; w += (size_t)NCH * 8192 * 4;   // 1 MB

    ln_kernel<<<M_DIM, 256, 0, stream>>>(x, gamma, beta, xn);
    wt_kernel<<<dim3(K_DIM / 64, N_DIM / 64), 256, 0, stream>>>(W, Wt);
    gemm_kernel<<<dim3(M_DIM / 128, N_DIM / 128), 256, 0, stream>>>(xn, Wt, b, ug, fg, rg);
    scan1_kernel<<<dim3(NCH, 16), 256, 0, stream>>>(fg, ug, Aa, Ss);
    scan2_kernel<<<32, 256, 0, stream>>>(Aa, Ss, c0, cs, lastc);
    scan3_kernel<<<dim3(NCH, 16), 256, 0, stream>>>(cs, fg, ug, rg, xn, x, out);
}

// Round 2
// 215.824 us; speedup vs baseline: 1.1111x; 1.1111x over previous
//
#include <hip/hip_runtime.h>
#include <hip/hip_bf16.h>

// SRU layer: LN -> bf16 MFMA GEMM (256^2 8-phase template) -> chunked scan.
// L=2048, B=8, D=1024, M=16384, K=1024, N=3072.

typedef unsigned short u16;
typedef __bf16 bf16x8 __attribute__((ext_vector_type(8)));
typedef float f32x4 __attribute__((ext_vector_type(4)));

#define L_DIM 2048
#define B_DIM 8
#define D_DIM 1024
#define M_DIM (L_DIM * B_DIM)   // 16384
#define K_DIM D_DIM             // 1024
#define N_DIM (3 * D_DIM)       // 3072
#define NCH 32
#define CLEN (L_DIM / NCH)      // 64
#define NT (K_DIM / 64)         // 16 K-tiles

// GEMM LDS layout (bytes): A bufs [0,64K), B bufs [64K,128K), dummy [128K,144K)
#define LDS_A 0
#define LDS_B 65536
#define LDS_DUMMY 131072
#define LDS_TOTAL 147456

__device__ __forceinline__ float bf2f(u16 h) {
    unsigned int u = ((unsigned int)h) << 16;
    float f;
    __builtin_memcpy(&f, &u, 4);
    return f;
}

__device__ __forceinline__ u16 f2bf(float f) {
    unsigned int u;
    __builtin_memcpy(&u, &f, 4);
    u = u + 0x7fff + ((u >> 16) & 1);   // RNE
    return (u16)(u >> 16);
}

__device__ __forceinline__ void async16(void* lds, const void* g) {
    __builtin_amdgcn_global_load_lds(
        (const __attribute__((address_space(1))) void*)g,
        (__attribute__((address_space(3))) void*)lds, 16, 0, 0);
}

// ---------------- LayerNorm ----------------
__global__ __launch_bounds__(256) void ln_kernel(const float* __restrict__ x,
                                                 const float* __restrict__ gamma,
                                                 const float* __restrict__ beta,
                                                 u16* __restrict__ xn) {
    int row = blockIdx.x;
    int tid = threadIdx.x;
    const float4* xr = (const float4*)(x + (size_t)row * D_DIM);
    float4 v = xr[tid];
    float s = v.x + v.y + v.z + v.w;
    float q = v.x * v.x + v.y * v.y + v.z * v.z + v.w * v.w;
    #pragma unroll
    for (int off = 32; off; off >>= 1) {
        s += __shfl_down(s, off);
        q += __shfl_down(q, off);
    }
    __shared__ float ss[4], qq[4];
    int lane = tid & 63, wv = tid >> 6;
    if (lane == 0) { ss[wv] = s; qq[wv] = q; }
    __syncthreads();
    s = ss[0] + ss[1] + ss[2] + ss[3];
    q = qq[0] + qq[1] + qq[2] + qq[3];
    float mu = s * (1.0f / D_DIM);
    float var = q * (1.0f / D_DIM) - mu * mu;
    float rs = rsqrtf(var + 1e-5f);
    float4 g = ((const float4*)gamma)[tid];
    float4 bt = ((const float4*)beta)[tid];
    ushort4 o;
    o.x = f2bf((v.x - mu) * rs * g.x + bt.x);
    o.y = f2bf((v.y - mu) * rs * g.y + bt.y);
    o.z = f2bf((v.z - mu) * rs * g.z + bt.z);
    o.w = f2bf((v.w - mu) * rs * g.w + bt.w);
    ((ushort4*)(xn + (size_t)row * D_DIM))[tid] = o;
}

// ---------------- W transpose+convert: W[K][N] f32 -> Wt[N][K] bf16 ----------------
__global__ __launch_bounds__(256) void wt_kernel(const float* __restrict__ W,
                                                 u16* __restrict__ Wt) {
    __shared__ float t[64][65];
    int k0 = blockIdx.x * 64;
    int n0 = blockIdx.y * 64;
    int col = threadIdx.x & 63;
    int rg4 = threadIdx.x >> 6;
    #pragma unroll
    for (int j = 0; j < 16; ++j) {
        int r = rg4 * 16 + j;
        t[r][col] = W[(size_t)(k0 + r) * N_DIM + n0 + col];
    }
    __syncthreads();
    #pragma unroll
    for (int j = 0; j < 16; ++j) {
        int nr = rg4 * 16 + j;
        Wt[(size_t)(n0 + nr) * K_DIM + k0 + col] = f2bf(t[col][nr]);
    }
}

// ---------------- GEMM: 256x256 tile, BK=64, 8 waves, 8-phase counted-vmcnt ----------------
// Staging stream per K-tile t (1 half-tile/phase, strictly race-safe targets):
//   phase a: A-h0(t+1)  [opposite buf, fully read 2 phases ago]
//   phase b: A-h1(t+1)
//   phase g: B-h0(t+2)  [same buf; B reads of tile t completed at phase b + barrier]
//   phase d: B-h1(t+2)  + s_waitcnt vmcnt(4)  -> tile t+1 fully landed
__device__ __forceinline__ void stage_half(const u16* __restrict__ gsrc, int base0,
                                           int t, int h, char* lds, int ldsOp,
                                           int tid, int wave) {
    int tc = (t < NT) ? t : 0;
    int k0 = tc * 64;
    char* dst0 = (t < NT) ? (lds + ldsOp + (t & 1) * 32768 + h * 16384)
                          : (lds + LDS_DUMMY);
    #pragma unroll
    for (int s = 0; s < 2; ++s) {
        int c = s * 512 + tid;
        int row = h * 128 + (c >> 3);
        int cc = (c & 7) ^ (row & 7);   // pre-swizzled global source (rule 21)
        async16(dst0 + s * 8192 + wave * 1024,
                gsrc + (size_t)(base0 + row) * K_DIM + k0 + cc * 8);
    }
}

__global__ __launch_bounds__(512, 2) void gemm_kernel(const u16* __restrict__ A,
                                                      const u16* __restrict__ Bt,
                                                      const float* __restrict__ bias,
                                                      u16* __restrict__ uo,
                                                      u16* __restrict__ fo,
                                                      u16* __restrict__ ro) {
    extern __shared__ char lds[];
    const int tid = threadIdx.x;
    const int wave = tid >> 6, lane = tid & 63;
    const int lm = lane & 15, lg = lane >> 4;
    const int wm = wave >> 2, wn = wave & 3;   // 2M x 4N waves
    const int m0 = blockIdx.x * 256;
    const int n0 = blockIdx.y * 256;

    f32x4 acc[8][4] = {};
    bf16x8 av[4][2], aw[4][2], bv[4][2];

#define LDA(dst, bb, mf0)                                                       \
    do { _Pragma("unroll")                                                      \
        for (int q = 0; q < 4; ++q) {                                           \
            int row_ = wm * 128 + ((mf0) + q) * 16 + lm;                        \
            const char* p_ = lds + LDS_A + (bb) * 32768 + row_ * 128;           \
            _Pragma("unroll")                                                   \
            for (int kk = 0; kk < 2; ++kk)                                      \
                dst[q][kk] = *(const bf16x8*)(p_ + ((((kk << 2) | lg) ^ (row_ & 7)) << 4)); \
        } } while (0)

#define LDB(bb, kk)                                                             \
    do { _Pragma("unroll")                                                      \
        for (int nf = 0; nf < 4; ++nf) {                                        \
            int row_ = wn * 64 + nf * 16 + lm;                                  \
            bv[nf][kk] = *(const bf16x8*)(lds + LDS_B + (bb) * 32768 + row_ * 128 \
                                          + ((((kk << 2) | lg) ^ (row_ & 7)) << 4)); \
        } } while (0)

#define MFMA16(r0, afr, kk)                                                     \
    do { _Pragma("unroll")                                                      \
        for (int q = 0; q < 4; ++q)                                             \
            _Pragma("unroll")                                                   \
            for (int nf = 0; nf < 4; ++nf)                                      \
                acc[(r0) + q][nf] = __builtin_amdgcn_mfma_f32_16x16x32_bf16(    \
                    afr[q][kk], bv[nf][kk], acc[(r0) + q][nf], 0, 0, 0);        \
    } while (0)

#define PH_SYNC()                                                               \
    do { __builtin_amdgcn_s_barrier();                                          \
         asm volatile("s_waitcnt lgkmcnt(0)");                                  \
         __builtin_amdgcn_sched_barrier(0); } while (0)

#define TILE_BODY(t, bb, last)                                                  \
    do {                                                                        \
        /* phase a: A mf0-3 (both kk) + B kk0 reads; stage A-h0(t+1) */         \
        LDA(av, bb, 0);                                                         \
        LDB(bb, 0);                                                             \
        stage_half(A, m0, (t) + 1, 0, lds, LDS_A, tid, wave);                   \
        PH_SYNC();                                                              \
        __builtin_amdgcn_s_setprio(1);                                          \
        MFMA16(0, av, 0);                                                       \
        __builtin_amdgcn_s_setprio(0);                                          \
        __builtin_amdgcn_s_barrier();                                           \
        /* phase b: B kk1 reads; stage A-h1(t+1) */                             \
        LDB(bb, 1);                                                             \
        stage_half(A, m0, (t) + 1, 1, lds, LDS_A, tid, wave);                   \
        PH_SYNC();                                                              \
        __builtin_amdgcn_s_setprio(1);                                          \
        MFMA16(0, av, 1);                                                       \
        __builtin_amdgcn_s_setprio(0);                                          \
        __builtin_amdgcn_s_barrier();                                           \
        /* phase g: A mf4-7 reads; stage B-h0(t+2) */                           \
        LDA(aw, bb, 4);                                                         \
        stage_half(Bt, n0, (t) + 2, 0, lds, LDS_B, tid, wave);                  \
        PH_SYNC();                                                              \
        __builtin_amdgcn_s_setprio(1);                                          \
        MFMA16(4, aw, 0);                                                       \
        __builtin_amdgcn_s_setprio(0);                                          \
        __builtin_amdgcn_s_barrier();                                           \
        /* phase d: no reads; stage B-h1(t+2); counted vmcnt */                 \
        stage_half(Bt, n0, (t) + 2, 1, lds, LDS_B, tid, wave);                  \
        __builtin_amdgcn_s_barrier();                                           \
        __builtin_amdgcn_s_setprio(1);                                          \
        MFMA16(4, aw, 1);                                                       \
        __builtin_amdgcn_s_setprio(0);                                          \
        if (!(last)) asm volatile("s_waitcnt vmcnt(4)" ::: "memory");           \
        __builtin_amdgcn_s_barrier();                                           \
    } while (0)

    // prologue: tile 0 (A+B) + tile 1 (B halves); vmcnt(4) -> tile 0 landed
    stage_half(A, m0, 0, 0, lds, LDS_A, tid, wave);
    stage_half(A, m0, 0, 1, lds, LDS_A, tid, wave);
    stage_half(Bt, n0, 0, 0, lds, LDS_B, tid, wave);
    stage_half(Bt, n0, 0, 1, lds, LDS_B, tid, wave);
    stage_half(Bt, n0, 1, 0, lds, LDS_B, tid, wave);
    stage_half(Bt, n0, 1, 1, lds, LDS_B, tid, wave);
    asm volatile("s_waitcnt vmcnt(4)" ::: "memory");
    __builtin_amdgcn_s_barrier();

    for (int t = 0; t < NT - 2; t += 2) {
        TILE_BODY(t, 0, 0);
        TILE_BODY(t + 1, 1, 0);
    }
    TILE_BODY(NT - 2, 0, 0);
    TILE_BODY(NT - 1, 1, 1);

    // epilogue: bias + sigmoid (f/r), bf16 store
    int seg = n0 >> 10;   // uniform per block (256 | 1024)
    u16* outp = (seg == 0) ? uo : ((seg == 1) ? fo : ro);
    #pragma unroll
    for (int mf = 0; mf < 8; ++mf) {
        #pragma unroll
        for (int nf = 0; nf < 4; ++nf) {
            int col = n0 + wn * 64 + nf * 16 + lm;
            int cm = col & 1023;
            float bb2 = bias[col];
            #pragma unroll
            for (int j = 0; j < 4; ++j) {
                int row = m0 + wm * 128 + mf * 16 + lg * 4 + j;
                float val = acc[mf][nf][j] + bb2;
                if (seg != 0) val = 1.0f / (1.0f + __expf(-val));
                outp[(size_t)row * D_DIM + cm] = f2bf(val);
            }
        }
    }
#undef LDA
#undef LDB
#undef MFMA16
#undef PH_SYNC
#undef TILE_BODY
}

// ---------------- Scan phase 1 ----------------
__global__ __launch_bounds__(256) void scan1_kernel(const u16* __restrict__ fg,
                                                    const u16* __restrict__ u,
                                                    float* __restrict__ Aa,
                                                    float* __restrict__ Ss) {
    int ch = blockIdx.x;
    int bd = (blockIdx.y * 256 + threadIdx.x) * 2;
    int b = bd >> 10, d = bd & 1023;
    float a0 = 1.0f, a1 = 1.0f, s0 = 0.0f, s1 = 0.0f;
    for (int t = ch * CLEN; t < ch * CLEN + CLEN; ++t) {
        size_t idx = ((size_t)(t * B_DIM + b) << 10) + d;
        ushort2 f2 = *(const ushort2*)(fg + idx);
        ushort2 u2 = *(const ushort2*)(u + idx);
        float f0 = bf2f(f2.x), f1 = bf2f(f2.y);
        float v0 = bf2f(u2.x), v1 = bf2f(u2.y);
        s0 = f0 * s0 + (1.0f - f0) * v0;
        s1 = f1 * s1 + (1.0f - f1) * v1;
        a0 *= f0;
        a1 *= f1;
    }
    int o = ch * 8192 + bd;
    *(float2*)(Aa + o) = make_float2(a0, a1);
    *(float2*)(Ss + o) = make_float2(s0, s1);
}

// ---------------- Scan phase 2 ----------------
__global__ __launch_bounds__(256) void scan2_kernel(const float* __restrict__ Aa,
                                                    const float* __restrict__ Ss,
                                                    const float* __restrict__ c0,
                                                    float* __restrict__ cs,
                                                    float* __restrict__ lastc) {
    int bd = blockIdx.x * 256 + threadIdx.x;
    float c = c0[bd];
    #pragma unroll 4
    for (int ch = 0; ch < NCH; ++ch) {
        cs[ch * 8192 + bd] = c;
        c = Aa[ch * 8192 + bd] * c + Ss[ch * 8192 + bd];
    }
    lastc[bd] = c;
}

// ---------------- Scan phase 3 ----------------
__global__ __launch_bounds__(256) void scan3_kernel(const float* __restrict__ cs,
                                                    const u16* __restrict__ fg,
                                                    const u16* __restrict__ u,
                                                    const u16* __restrict__ rg,
                                                    const u16* __restrict__ xn,
                                                    const float* __restrict__ x,
                                                    float* __restrict__ out) {
    int ch = blockIdx.x;
    int bd = (blockIdx.y * 256 + threadIdx.x) * 2;
    int b = bd >> 10, d = bd & 1023;
    float c0v = cs[ch * 8192 + bd];
    float c1v = cs[ch * 8192 + bd + 1];
    for (int t = ch * CLEN; t < ch * CLEN + CLEN; ++t) {
        size_t idx = ((size_t)(t * B_DIM + b) << 10) + d;
        ushort2 f2 = *(const ushort2*)(fg + idx);
        ushort2 u2 = *(const ushort2*)(u + idx);
        ushort2 r2 = *(const ushort2*)(rg + idx);
        ushort2 n2 = *(const ushort2*)(xn + idx);
        float2 x2 = *(const float2*)(x + idx);
        float f0 = bf2f(f2.x), f1 = bf2f(f2.y);
        float v0 = bf2f(u2.x), v1 = bf2f(u2.y);
        float r0 = bf2f(r2.x), r1 = bf2f(r2.y);
        float n0 = bf2f(n2.x), n1 = bf2f(n2.y);
        c0v = f0 * c0v + (1.0f - f0) * v0;
        c1v = f1 * c1v + (1.0f - f1) * v1;
        float h0 = r0 * tanhf(c0v) + (1.0f - r0) * n0;
        float h1 = r1 * tanhf(c1v) + (1.0f - r1) * n1;
        *(float2*)(out + idx) = make_float2(x2.x + h0, x2.y + h1);
    }
}

extern "C" void kernel_launch(void* const* d_in, const int* in_sizes, int n_in,
                              void* d_out, int out_size, void* d_ws, size_t ws_size,
                              hipStream_t stream) {
    const float* x     = (const float*)d_in[0];
    const float* c0    = (const float*)d_in[1];
    const float* W     = (const float*)d_in[2];
    const float* b     = (const float*)d_in[3];
    const float* gamma = (const float*)d_in[4];
    const float* beta  = (const float*)d_in[5];
    float* out = (float*)d_out;
    float* lastc = out + (size_t)M_DIM * D_DIM;

    char* w = (char*)d_ws;
    u16* xn = (u16*)w;  w += (size_t)M_DIM * D_DIM * 2;
    u16* Wt = (u16*)w;  w += (size_t)N_DIM * K_DIM * 2;
    u16* ug = (u16*)w;  w += (size_t)M_DIM * D_DIM * 2;
    u16* fg = (u16*)w;  w += (size_t)M_DIM * D_DIM * 2;
    u16* rg = (u16*)w;  w += (size_t)M_DIM * D_DIM * 2;
    float* Aa = (float*)w; w += (size_t)NCH * 8192 * 4;
    float* Ss = (float*)w; w += (size_t)NCH * 8192 * 4;
    float* cs = (float*)w; w += (size_t)NCH * 8192 * 4;

    hipFuncSetAttribute(reinterpret_cast<const void*>(gemm_kernel),
                        hipFuncAttributeMaxDynamicSharedMemorySize, LDS_TOTAL);

    ln_kernel<<<M_DIM, 256, 0, stream>>>(x, gamma, beta, xn);
    wt_kernel<<<dim3(K_DIM / 64, N_DIM / 64), 256, 0, stream>>>(W, Wt);
    gemm_kernel<<<dim3(M_DIM / 256, N_DIM / 256), 512, LDS_TOTAL, stream>>>(xn, Wt, b, ug, fg, rg);
    scan1_kernel<<<dim3(NCH, 16), 256, 0, stream>>>(fg, ug, Aa, Ss);
    scan2_kernel<<<32, 256, 0, stream>>>(Aa, Ss, c0, cs, lastc);
    scan3_kernel<<<dim3(NCH, 16), 256, 0, stream>>>(cs, fg, ug, rg, xn, x, out);
}